// Round 1
// baseline (363.017 us; speedup 1.0000x reference)
//
#include <hip/hip_runtime.h>

// B=8, N=256, D_IN=D_OUT=128
// out[b,i,d] = sum_e T[b,i,e] * W[e,d] + bias[d]
//   where T[b,i,e] = sum_j adj[b,i,j] * (hidden[b,j,e] + dep[b,j,i,e])
// (einsum reassociation: avoids materializing the 256 MiB fusion tensor and
//  cuts 17.2 GFLOP -> ~0.3 GFLOP; kernel is HBM-read-bound on dep_embed.)

constexpr int Bc = 8;
constexpr int Nc = 256;
constexpr int Dc = 128;

__global__ __launch_bounds__(256, 2) void depgcn_kernel(
    const float* __restrict__ hidden,  // [B,N,D]
    const float* __restrict__ adj,     // [B,N,N]
    const float* __restrict__ dep,     // [B,N,N,D]
    const float* __restrict__ W,       // [D,D]
    const float* __restrict__ bias,    // [D]
    float* __restrict__ out)           // [B,N,D]
{
    const int bi = blockIdx.x;        // 0 .. B*N-1
    const int b  = bi >> 8;           // / N
    const int i  = bi & (Nc - 1);
    const int t  = threadIdx.x;       // 0..255
    const int g  = t >> 5;            // j-partition 0..7
    const int c  = t & 31;            // float4 channel: e = 4c..4c+3

    __shared__ float sAdj[Nc];
    __shared__ float sP[8][Dc];       // per-partition partial T
    __shared__ float sT[Dc];
    __shared__ float sO[2][Dc];

    // stage adj row (broadcast source for the j-loop)
    sAdj[t] = adj[((size_t)b * Nc + i) * Nc + t];
    __syncthreads();

    // dep[b, j, i, 4c] ; j-stride = N*D floats (128 KB)
    const float* depP = dep + (((size_t)b * Nc) * Nc + i) * Dc + (size_t)c * 4;
    const float* hidP = hidden + ((size_t)b * Nc) * Dc + (size_t)c * 4;

    float4 acc = make_float4(0.f, 0.f, 0.f, 0.f);
    #pragma unroll 4
    for (int j = g; j < Nc; j += 8) {
        const float  a  = sAdj[j];
        const float4 d4 = *(const float4*)(depP + (size_t)j * Nc * Dc);
        const float4 h4 = *(const float4*)(hidP + (size_t)j * Dc);
        acc.x = fmaf(a, d4.x + h4.x, acc.x);
        acc.y = fmaf(a, d4.y + h4.y, acc.y);
        acc.z = fmaf(a, d4.z + h4.z, acc.z);
        acc.w = fmaf(a, d4.w + h4.w, acc.w);
    }
    *(float4*)&sP[g][c * 4] = acc;
    __syncthreads();

    // reduce the 8 j-partitions -> T[b,i,e]
    if (t < Dc) {
        float s = 0.f;
        #pragma unroll
        for (int gg = 0; gg < 8; ++gg) s += sP[gg][t];
        sT[t] = s;
    }
    __syncthreads();

    // out[b,i,d] = sum_e sT[e]*W[e,d] + bias[d]; split e-range over 2 halves
    {
        const int d = t & (Dc - 1);
        const int h = t >> 7;                  // 0 or 1
        const float* wp = W + (size_t)(h * 64) * Dc + d;
        float s = 0.f;
        #pragma unroll 8
        for (int e = 0; e < 64; ++e)
            s = fmaf(sT[h * 64 + e], wp[(size_t)e * Dc], s);
        sO[h][d] = s;
    }
    __syncthreads();

    if (t < Dc) {
        out[((size_t)b * Nc + i) * Dc + t] = sO[0][t] + sO[1][t] + bias[t];
    }
}

extern "C" void kernel_launch(void* const* d_in, const int* in_sizes, int n_in,
                              void* d_out, int out_size, void* d_ws, size_t ws_size,
                              hipStream_t stream) {
    const float* hidden = (const float*)d_in[0];
    const float* adj    = (const float*)d_in[1];
    const float* dep    = (const float*)d_in[2];
    const float* W      = (const float*)d_in[3];
    const float* bias   = (const float*)d_in[4];
    float* out          = (float*)d_out;

    depgcn_kernel<<<dim3(Bc * Nc), dim3(256), 0, stream>>>(hidden, adj, dep, W, bias, out);
}